// Round 4
// baseline (380.684 us; speedup 1.0000x reference)
//
#include <hip/hip_runtime.h>

#define MAXG 4
#define CPB 8                        // channels per block = 4 pairs
#define UCOLS 33                     // region cols 0..32 per row
#define PLANE 990                    // float2 per pair-plane (30*33), no pad
#define BUFL (4 * PLANE)             // 3960 float2 = 31680 B per buffer
#define RPB 4                        // rois per block, LDS-double-buffered

// Round-4: double-buffered pipeline, fixing R2's mistakes.
//   iter i: issue global loads(roi i+1) -> regs     (HBM latency in flight)
//           write tables(i+1) -> table-buf^1        (disjoint from cur reads)
//           compute(roi i) from feat-buf cur        (covers the latency)
//           ds_write regs -> feat-buf^1             (vmcnt-gated, disjoint)
//           ONE __syncthreads(); swap
// LDS = 2*31680 (feat) + 2*896 (tables) = 65152 B <= 64 KB -> 2 blocks/CU,
// 8 waves/CU; between barriers stalled waves are covered by siblings.
// R1..R3 falsified: occupancy bump (null), single-buffer reg pipeline (-12us),
// Morton/XCD locality (-20us). This is the last unfalsified lever: if neutral,
// the kernel is at its balanced floor (~75% of achievable BW on requested bytes).

struct RoiS {
    float x1, y1, bin_h, bin_w;
    int   gh, gw;
    float inv_count;
    int   y0, x0a, rh, spanA, CM;
    const float* fbase;              // feat + (b*C + c0)*HW + y0*W + x0a
};

__device__ __forceinline__ int lo_of(float pos, int size) {
    float pp = fmaxf(pos, 0.0f);
    return min((int)floorf(pp), size - 1);
}

__device__ __forceinline__ RoiS make_scalars(const float* __restrict__ rois, int n,
                                             const float* __restrict__ feat,
                                             int C, int c0, int H, int W, size_t HW) {
    RoiS s;
    const float* roi = rois + (size_t)n * 5;
    const int   b  = (int)roi[0];
    const float x1 = roi[1], y1 = roi[2], x2 = roi[3], y2 = roi[4];
    const float roi_w = fmaxf(x2 - x1, 1.0f);
    const float roi_h = fmaxf(y2 - y1, 1.0f);
    s.bin_h = roi_h / 7.0f;
    s.bin_w = roi_w / 7.0f;
    int gh = (int)ceilf(roi_h / 7.0f); gh = min(max(gh, 1), MAXG);
    int gw = (int)ceilf(roi_w / 7.0f); gw = min(max(gw, 1), MAXG);
    s.gh = gh; s.gw = gw;
    s.inv_count = 1.0f / (float)(gh * gw);
    s.x1 = x1; s.y1 = y1;
    s.y0 = lo_of(y1 + 0.5f * s.bin_h / (float)gh, H);
    int yE = min(lo_of(y1 + 6.0f * s.bin_h + ((float)(gh - 1) + 0.5f) * s.bin_h / (float)gh, H) + 1, H - 1);
    int x0 = lo_of(x1 + 0.5f * s.bin_w / (float)gw, W);
    int xE = min(lo_of(x1 + 6.0f * s.bin_w + ((float)(gw - 1) + 0.5f) * s.bin_w / (float)gw, W) + 1, W - 1);
    s.rh    = min(yE - s.y0 + 1, 30);
    s.x0a   = x0 & ~3;               // 16B-align region start
    s.spanA = min(xE - s.x0a + 1, 33);
    s.CM    = W - 4 - s.x0a;
    s.fbase = feat + ((size_t)b * C + c0) * HW + (size_t)s.y0 * W + s.x0a;
    return s;
}

__device__ __forceinline__ void issue_loads(const RoiS& s, int p, int q, int q4, int r0,
                                            size_t HW, int W,
                                            float4 va[4], float4 vb[4], float tc[4][2]) {
    const bool qon  = (q4 < s.spanA);
    const int  colA = min(q4, s.CM);
    const bool tail = (q == 7) && (s.spanA == 33);
    const float* ga = s.fbase + (size_t)(2 * p) * HW;
    #pragma unroll
    for (int k = 0; k < 4; ++k) {
        const int r = r0 + (k << 3);
        if (r < s.rh) {
            const float* gp = ga + (size_t)r * W;
            if (qon) {
                va[k] = *(const float4*)(gp + colA);
                vb[k] = *(const float4*)(gp + HW + colA);
            }
            if (tail) { tc[k][0] = gp[32]; tc[k][1] = gp[HW + 32]; }
        }
    }
}

__device__ __forceinline__ void write_lds(const RoiS& s, int p, int q, int q4, int r0,
                                          float2* __restrict__ sbuf,
                                          const float4 va[4], const float4 vb[4],
                                          const float tc[4][2]) {
    const bool qon  = (q4 < s.spanA);
    const int  colA = min(q4, s.CM);
    const bool tail = (q == 7) && (s.spanA == 33);
    float2* sb = sbuf + p * PLANE;
    #pragma unroll
    for (int k = 0; k < 4; ++k) {
        const int r = r0 + (k << 3);
        if (r < s.rh) {
            if (qon) {
                float2* sp = sb + r * UCOLS + colA;
                sp[0] = make_float2(va[k].x, vb[k].x);
                sp[1] = make_float2(va[k].y, vb[k].y);
                sp[2] = make_float2(va[k].z, vb[k].z);
                sp[3] = make_float2(va[k].w, vb[k].w);
            }
            if (tail) sb[r * UCOLS + 32] = make_float2(tc[k][0], tc[k][1]);
        }
    }
}

__device__ __forceinline__ void write_tables(const RoiS& s, int t, int H, int W,
                                             int4* __restrict__ ypack,
                                             int4* __restrict__ xpack) {
    if (t < 28) {
        const int py = t >> 2, g = t & 3;
        float pos  = s.y1 + (float)py * s.bin_h + ((float)g + 0.5f) * s.bin_h / (float)s.gh;
        bool valid = (pos >= -1.0f) && (pos <= (float)H);
        float pp = fmaxf(pos, 0.0f);
        int lo  = min((int)floorf(pp), H - 1);
        int hi  = min(lo + 1, H - 1);
        if (lo >= H - 1) pp = (float)(H - 1);
        float frac = pp - (float)lo;
        float m = valid ? 1.0f : 0.0f;
        ypack[t] = make_int4((lo - s.y0) * UCOLS, (hi - s.y0) * UCOLS,
                             __float_as_int((1.0f - frac) * m),
                             __float_as_int(frac * m));
    } else if (t < 56) {
        const int u = t - 28;
        const int px = u >> 2, g = u & 3;
        float pos  = s.x1 + (float)px * s.bin_w + ((float)g + 0.5f) * s.bin_w / (float)s.gw;
        bool valid = (pos >= -1.0f) && (pos <= (float)W);
        float pp = fmaxf(pos, 0.0f);
        int lo  = min((int)floorf(pp), W - 1);
        int hi  = min(lo + 1, W - 1);
        if (lo >= W - 1) pp = (float)(W - 1);
        float frac = pp - (float)lo;
        float m = valid ? 1.0f : 0.0f;
        xpack[u] = make_int4(lo - s.x0a, hi - s.x0a,
                             __float_as_int((1.0f - frac) * m),
                             __float_as_int(frac * m));
    }
}

__device__ __forceinline__ void compute_out(const RoiS& s, int n, int cblk, int t,
                                            const float2* __restrict__ sbuf,
                                            const int4* __restrict__ ypack,
                                            const int4* __restrict__ xpack,
                                            float* __restrict__ out, int C) {
    if (t < 196) {
        const int p   = t & 3;
        const int pix = t >> 2;
        const int py  = pix / 7;
        const int px  = pix - py * 7;
        const float2* sp = sbuf + p * PLANE;

        int4 xp[4];
        #pragma unroll
        for (int g = 0; g < 4; ++g) xp[g] = xpack[(px << 2) + g];

        float ax = 0.0f, ay = 0.0f;
        #pragma unroll
        for (int gy = 0; gy < MAXG; ++gy) {
            if (gy < s.gh) {
                const int4 yp = ypack[(py << 2) + gy];
                const float wy0 = __int_as_float(yp.z);
                const float wy1 = __int_as_float(yp.w);
                #pragma unroll
                for (int gx = 0; gx < MAXG; ++gx) {
                    if (gx < s.gw) {
                        const float wx0 = __int_as_float(xp[gx].z);
                        const float wx1 = __int_as_float(xp[gx].w);
                        const float2 v00 = sp[yp.x + xp[gx].x];
                        const float2 v01 = sp[yp.x + xp[gx].y];
                        const float2 v10 = sp[yp.y + xp[gx].x];
                        const float2 v11 = sp[yp.y + xp[gx].y];
                        ax += wy0 * (wx0 * v00.x + wx1 * v01.x)
                            + wy1 * (wx0 * v10.x + wx1 * v11.x);
                        ay += wy0 * (wx0 * v00.y + wx1 * v01.y)
                            + wy1 * (wx0 * v10.y + wx1 * v11.y);
                    }
                }
            }
        }
        const size_t ob = ((size_t)n * C + cblk * CPB + 2 * p) * 49 + pix;
        out[ob]      = ax * s.inv_count;   // channel 2p
        out[ob + 49] = ay * s.inv_count;   // channel 2p+1
    }
}

__global__ __launch_bounds__(256, 2) void roi_align_kernel(
    const float* __restrict__ feat,
    const float* __restrict__ rois,
    float* __restrict__ out,
    int C, int H, int W, int N)
{
    const int n0   = blockIdx.x * RPB;
    const int cblk = blockIdx.y;
    const int t    = threadIdx.x;

    __shared__ float2 s_feat2[2 * BUFL];     // 63360 B
    __shared__ int4   s_ypack[2][28];        // + 896 B
    __shared__ int4   s_xpack[2][28];        // + 896 B   total 65152 <= 64 KB

    const size_t HW = (size_t)H * W;
    const int c0 = cblk * CPB;

    const int p  = t & 3;
    const int q  = (t >> 2) & 7;
    const int r0 = t >> 5;
    const int q4 = q << 2;

    float4 va[4], vb[4];
    float  tc[4][2];

    // prologue: stage roi n0 into buffer 0
    RoiS cur = make_scalars(rois, n0, feat, C, c0, H, W, HW);
    issue_loads(cur, p, q, q4, r0, HW, W, va, vb, tc);
    write_tables(cur, t, H, W, s_ypack[0], s_xpack[0]);
    write_lds(cur, p, q, q4, r0, s_feat2, va, vb, tc);
    __syncthreads();

    int buf = 0;
    #pragma unroll
    for (int i = 0; i < RPB; ++i) {
        RoiS nxt;
        if (i + 1 < RPB) {
            // stage roi i+1 into the OTHER buffer: loads in flight across compute
            nxt = make_scalars(rois, n0 + i + 1, feat, C, c0, H, W, HW);
            issue_loads(nxt, p, q, q4, r0, HW, W, va, vb, tc);
            write_tables(nxt, t, H, W, s_ypack[buf ^ 1], s_xpack[buf ^ 1]);
        }
        compute_out(cur, n0 + i, cblk, t,
                    s_feat2 + buf * BUFL, s_ypack[buf], s_xpack[buf], out, C);
        if (i + 1 < RPB) {
            write_lds(nxt, p, q, q4, r0, s_feat2 + (buf ^ 1) * BUFL, va, vb, tc);
        }
        __syncthreads();             // buf^1 staged AND buf reads done
        buf ^= 1;
        cur = nxt;
    }
}

extern "C" void kernel_launch(void* const* d_in, const int* in_sizes, int n_in,
                              void* d_out, int out_size, void* d_ws, size_t ws_size,
                              hipStream_t stream) {
    const float* feat = (const float*)d_in[0];
    const float* rois = (const float*)d_in[1];
    float* out = (float*)d_out;

    const int C = 256, H = 200, W = 272;
    const int N = in_sizes[1] / 5;   // 512 (divisible by RPB)

    dim3 grid(N / RPB, C / CPB);     // 128 x 32
    roi_align_kernel<<<grid, 256, 0, stream>>>(feat, rois, out, C, H, W, N);
}

// Round 5
// 332.632 us; speedup vs baseline: 1.1445x; 1.1445x over previous
//
#include <hip/hip_runtime.h>

#define MAXG 4
#define CPB 8                        // channels per block = 4 pairs
#define UCOLS 33                     // region cols 0..32 per row
#define PLANE 991                    // float2 per pair-plane: 30*33=990 used +1 pad
                                     // (991*2 mod 32 = 30: odd bank-pair spread across planes — do NOT use 990)
#define S2LEN (4 * PLANE)            // 3964 float2 = 31712 B

// Round-5: exact round-1 body (known-best, kernel ~57us), ONE change:
// grid dims swapped to (cblk fast, n slow). The 32 channel-group blocks of the
// same ROI now dispatch at consecutive linear ids -> contemporaneously across
// the 8 XCDs -> each XCD L2 fetches the ~26KB ROI region once and serves ~4
// channel-groups from L2 instead of paying L3 service 32 times per region.
// Falsified so far: +occupancy (R1 null), reg pipeline (R2 -12us), Morton sort
// +%8 decode (R3 -20us), LDS double-buffer (R4 -57us). FETCH_SIZE measured at
// ~218MB = compulsory (poison fills evict L3); HBM floor ~36us kernel.
__global__ __launch_bounds__(256, 5) void roi_align_kernel(
    const float* __restrict__ feat,
    const float* __restrict__ rois,
    float* __restrict__ out,
    int C, int H, int W)
{
    const int cblk = blockIdx.x;     // FAST dim: 32 same-roi blocks adjacent in dispatch
    const int n    = blockIdx.y;
    const int t    = threadIdx.x;

    __shared__ float2 s_feat2[S2LEN];
    __shared__ int4   s_ypack[28];   // {(lo-y0)*33, (hi-y0)*33, bits(wy0), bits(wy1)}
    __shared__ int4   s_xpack[28];   // {(xlo-x0a), (xhi-x0a), bits(wx0), bits(wx1)}

    const float* roi = rois + (size_t)n * 5;
    const int   b  = (int)roi[0];
    const float x1 = roi[1], y1 = roi[2], x2 = roi[3], y2 = roi[4];
    const float roi_w = fmaxf(x2 - x1, 1.0f);
    const float roi_h = fmaxf(y2 - y1, 1.0f);
    const float bin_h = roi_h / 7.0f;
    const float bin_w = roi_w / 7.0f;
    int gh = (int)ceilf(roi_h / 7.0f); gh = min(max(gh, 1), MAXG);
    int gw = (int)ceilf(roi_w / 7.0f); gw = min(max(gw, 1), MAXG);
    const float inv_count = 1.0f / (float)(gh * gw);

    auto lo_of = [](float pos, int size) {
        float p = fmaxf(pos, 0.0f);
        return min((int)floorf(p), size - 1);
    };
    const int y0 = lo_of(y1 + 0.5f * bin_h / (float)gh, H);
    const int yE = min(lo_of(y1 + 6.0f * bin_h + ((float)(gh - 1) + 0.5f) * bin_h / (float)gh, H) + 1, H - 1);
    const int x0 = lo_of(x1 + 0.5f * bin_w / (float)gw, W);
    const int xE = min(lo_of(x1 + 6.0f * bin_w + ((float)(gw - 1) + 0.5f) * bin_w / (float)gw, W) + 1, W - 1);
    const int rh    = min(yE - y0 + 1, 30);
    const int x0a   = x0 & ~3;                   // 16B-align region start
    const int spanA = min(xE - x0a + 1, 33);     // cols needed from x0a (<=33)
    const int CM    = W - 4 - x0a;               // max in-row aligned quad start

    // --- geometry tables (y offsets premultiplied into float2-index units)
    if (t < 28) {
        const int py = t >> 2, g = t & 3;
        float pos  = y1 + (float)py * bin_h + ((float)g + 0.5f) * bin_h / (float)gh;
        bool valid = (pos >= -1.0f) && (pos <= (float)H);
        float p = fmaxf(pos, 0.0f);
        int lo  = min((int)floorf(p), H - 1);
        int hi  = min(lo + 1, H - 1);
        if (lo >= H - 1) p = (float)(H - 1);
        float frac = p - (float)lo;
        float m = valid ? 1.0f : 0.0f;
        s_ypack[t] = make_int4((lo - y0) * UCOLS, (hi - y0) * UCOLS,
                               __float_as_int((1.0f - frac) * m),
                               __float_as_int(frac * m));
    } else if (t < 56) {
        const int u = t - 28;
        const int px = u >> 2, g = u & 3;
        float pos  = x1 + (float)px * bin_w + ((float)g + 0.5f) * bin_w / (float)gw;
        bool valid = (pos >= -1.0f) && (pos <= (float)W);
        float p = fmaxf(pos, 0.0f);
        int lo  = min((int)floorf(p), W - 1);
        int hi  = min(lo + 1, W - 1);
        if (lo >= W - 1) p = (float)(W - 1);
        float frac = p - (float)lo;
        float m = valid ? 1.0f : 0.0f;
        s_xpack[u] = make_int4(lo - x0a, hi - x0a,
                               __float_as_int((1.0f - frac) * m),
                               __float_as_int(frac * m));
    }

    // --- staging: transpose [ch][row][col] -> per-pair planes in LDS
    {
        const int  p    = t & 3;
        const int  q    = (t >> 2) & 7;
        const int  r0   = t >> 5;
        const int  q4   = q << 2;
        const bool qon  = (q4 < spanA);
        const int  colA = min(q4, CM);           // in-row aligned; dup writes benign
        const bool tail = (q == 7) && (spanA == 33);

        const size_t HW = (size_t)H * W;
        const int c0 = cblk * CPB;
        const float* fbase = feat + ((size_t)b * C + c0) * HW + (size_t)y0 * W + x0a;
        const float* ga = fbase + (size_t)(2 * p) * HW;
        float2* sb = s_feat2 + p * PLANE;

        #pragma unroll
        for (int k = 0; k < 4; ++k) {
            const int r = r0 + (k << 3);
            if (r < rh) {
                const float* gp = ga + (size_t)r * W;
                if (qon) {
                    const float4 va = *(const float4*)(gp + colA);
                    const float4 vb = *(const float4*)(gp + HW + colA);
                    float2* sp = sb + r * UCOLS + colA;
                    sp[0] = make_float2(va.x, vb.x);
                    sp[1] = make_float2(va.y, vb.y);
                    sp[2] = make_float2(va.z, vb.z);
                    sp[3] = make_float2(va.w, vb.w);
                }
                if (tail) {                      // col 32 (x0a+32 <= W-1 here)
                    sb[r * UCOLS + 32] = make_float2(gp[32], gp[HW + 32]);
                }
            }
        }
    }
    __syncthreads();

    // --- compute: thread = (pixel t>>2, channel-pair t&3); taps are b64 reads
    if (t < 196) {
        const int p   = t & 3;
        const int pix = t >> 2;
        const int py  = pix / 7;
        const int px  = pix - py * 7;
        const float2* sp = s_feat2 + p * PLANE;

        int4 xp[4];
        #pragma unroll
        for (int g = 0; g < 4; ++g) xp[g] = s_xpack[(px << 2) + g];

        float ax = 0.0f, ay = 0.0f;
        #pragma unroll
        for (int gy = 0; gy < MAXG; ++gy) {
            if (gy < gh) {
                const int4 yp = s_ypack[(py << 2) + gy];
                const float wy0 = __int_as_float(yp.z);
                const float wy1 = __int_as_float(yp.w);
                #pragma unroll
                for (int gx = 0; gx < MAXG; ++gx) {
                    if (gx < gw) {
                        const float wx0 = __int_as_float(xp[gx].z);
                        const float wx1 = __int_as_float(xp[gx].w);
                        const float2 v00 = sp[yp.x + xp[gx].x];
                        const float2 v01 = sp[yp.x + xp[gx].y];
                        const float2 v10 = sp[yp.y + xp[gx].x];
                        const float2 v11 = sp[yp.y + xp[gx].y];
                        ax += wy0 * (wx0 * v00.x + wx1 * v01.x)
                            + wy1 * (wx0 * v10.x + wx1 * v11.x);
                        ay += wy0 * (wx0 * v00.y + wx1 * v01.y)
                            + wy1 * (wx0 * v10.y + wx1 * v11.y);
                    }
                }
            }
        }
        const size_t ob = ((size_t)n * C + cblk * CPB + 2 * p) * 49 + pix;
        out[ob]      = ax * inv_count;   // channel 2p
        out[ob + 49] = ay * inv_count;   // channel 2p+1
    }
}

extern "C" void kernel_launch(void* const* d_in, const int* in_sizes, int n_in,
                              void* d_out, int out_size, void* d_ws, size_t ws_size,
                              hipStream_t stream) {
    const float* feat = (const float*)d_in[0];
    const float* rois = (const float*)d_in[1];
    float* out = (float*)d_out;

    const int C = 256, H = 200, W = 272;
    const int N = in_sizes[1] / 5;   // 512

    dim3 grid(C / CPB, N);           // 32 x 512: cblk fast -> same-roi blocks adjacent
    roi_align_kernel<<<grid, 256, 0, stream>>>(feat, rois, out, C, H, W);
}

// Round 6
// 326.044 us; speedup vs baseline: 1.1676x; 1.0202x over previous
//
#include <hip/hip_runtime.h>

#define MAXG 4
#define CPB 8                        // channels per block = 4 pairs
#define UCOLS 33                     // region cols 0..32 per row
#define PLANE 991                    // float2 per pair-plane: 30*33=990 used +1 pad
                                     // (991*2 mod 32 = 30: odd bank-pair spread across planes — do NOT use 990)
#define S2LEN (4 * PLANE)            // 3964 float2 = 31712 B

// Round-6: restore the verified-best structure (R0/R1, 323.1/323.8 us; n fast,
// cblk slow) + nontemporal output stores (25MB write-only stream skips L2
// write-allocate). Falsified levers, each measured worse: +occupancy (null),
// reg pipeline (-12us), Morton/XCD (-20us), LDS dbuf (-57us), grid swap (-9us).
// Compulsory HBM = 238MB -> 35.5us kernel floor; this structure runs ~57us and
// no surviving lever addresses the gap.
__global__ __launch_bounds__(256, 5) void roi_align_kernel(
    const float* __restrict__ feat,
    const float* __restrict__ rois,
    float* __restrict__ out,
    int C, int H, int W)
{
    const int n    = blockIdx.x;
    const int cblk = blockIdx.y;
    const int t    = threadIdx.x;

    __shared__ float2 s_feat2[S2LEN];
    __shared__ int4   s_ypack[28];   // {(lo-y0)*33, (hi-y0)*33, bits(wy0), bits(wy1)}
    __shared__ int4   s_xpack[28];   // {(xlo-x0a), (xhi-x0a), bits(wx0), bits(wx1)}

    const float* roi = rois + (size_t)n * 5;
    const int   b  = (int)roi[0];
    const float x1 = roi[1], y1 = roi[2], x2 = roi[3], y2 = roi[4];
    const float roi_w = fmaxf(x2 - x1, 1.0f);
    const float roi_h = fmaxf(y2 - y1, 1.0f);
    const float bin_h = roi_h / 7.0f;
    const float bin_w = roi_w / 7.0f;
    int gh = (int)ceilf(roi_h / 7.0f); gh = min(max(gh, 1), MAXG);
    int gw = (int)ceilf(roi_w / 7.0f); gw = min(max(gw, 1), MAXG);
    const float inv_count = 1.0f / (float)(gh * gw);

    auto lo_of = [](float pos, int size) {
        float p = fmaxf(pos, 0.0f);
        return min((int)floorf(p), size - 1);
    };
    const int y0 = lo_of(y1 + 0.5f * bin_h / (float)gh, H);
    const int yE = min(lo_of(y1 + 6.0f * bin_h + ((float)(gh - 1) + 0.5f) * bin_h / (float)gh, H) + 1, H - 1);
    const int x0 = lo_of(x1 + 0.5f * bin_w / (float)gw, W);
    const int xE = min(lo_of(x1 + 6.0f * bin_w + ((float)(gw - 1) + 0.5f) * bin_w / (float)gw, W) + 1, W - 1);
    const int rh    = min(yE - y0 + 1, 30);
    const int x0a   = x0 & ~3;                   // 16B-align region start
    const int spanA = min(xE - x0a + 1, 33);     // cols needed from x0a (<=33)
    const int CM    = W - 4 - x0a;               // max in-row aligned quad start

    // --- geometry tables (y offsets premultiplied into float2-index units)
    if (t < 28) {
        const int py = t >> 2, g = t & 3;
        float pos  = y1 + (float)py * bin_h + ((float)g + 0.5f) * bin_h / (float)gh;
        bool valid = (pos >= -1.0f) && (pos <= (float)H);
        float p = fmaxf(pos, 0.0f);
        int lo  = min((int)floorf(p), H - 1);
        int hi  = min(lo + 1, H - 1);
        if (lo >= H - 1) p = (float)(H - 1);
        float frac = p - (float)lo;
        float m = valid ? 1.0f : 0.0f;
        s_ypack[t] = make_int4((lo - y0) * UCOLS, (hi - y0) * UCOLS,
                               __float_as_int((1.0f - frac) * m),
                               __float_as_int(frac * m));
    } else if (t < 56) {
        const int u = t - 28;
        const int px = u >> 2, g = u & 3;
        float pos  = x1 + (float)px * bin_w + ((float)g + 0.5f) * bin_w / (float)gw;
        bool valid = (pos >= -1.0f) && (pos <= (float)W);
        float p = fmaxf(pos, 0.0f);
        int lo  = min((int)floorf(p), W - 1);
        int hi  = min(lo + 1, W - 1);
        if (lo >= W - 1) p = (float)(W - 1);
        float frac = p - (float)lo;
        float m = valid ? 1.0f : 0.0f;
        s_xpack[u] = make_int4(lo - x0a, hi - x0a,
                               __float_as_int((1.0f - frac) * m),
                               __float_as_int(frac * m));
    }

    // --- staging: transpose [ch][row][col] -> per-pair planes in LDS
    {
        const int  p    = t & 3;
        const int  q    = (t >> 2) & 7;
        const int  r0   = t >> 5;
        const int  q4   = q << 2;
        const bool qon  = (q4 < spanA);
        const int  colA = min(q4, CM);           // in-row aligned; dup writes benign
        const bool tail = (q == 7) && (spanA == 33);

        const size_t HW = (size_t)H * W;
        const int c0 = cblk * CPB;
        const float* fbase = feat + ((size_t)b * C + c0) * HW + (size_t)y0 * W + x0a;
        const float* ga = fbase + (size_t)(2 * p) * HW;
        float2* sb = s_feat2 + p * PLANE;

        #pragma unroll
        for (int k = 0; k < 4; ++k) {
            const int r = r0 + (k << 3);
            if (r < rh) {
                const float* gp = ga + (size_t)r * W;
                if (qon) {
                    const float4 va = *(const float4*)(gp + colA);
                    const float4 vb = *(const float4*)(gp + HW + colA);
                    float2* sp = sb + r * UCOLS + colA;
                    sp[0] = make_float2(va.x, vb.x);
                    sp[1] = make_float2(va.y, vb.y);
                    sp[2] = make_float2(va.z, vb.z);
                    sp[3] = make_float2(va.w, vb.w);
                }
                if (tail) {                      // col 32 (x0a+32 <= W-1 here)
                    sb[r * UCOLS + 32] = make_float2(gp[32], gp[HW + 32]);
                }
            }
        }
    }
    __syncthreads();

    // --- compute: thread = (pixel t>>2, channel-pair t&3); taps are b64 reads
    if (t < 196) {
        const int p   = t & 3;
        const int pix = t >> 2;
        const int py  = pix / 7;
        const int px  = pix - py * 7;
        const float2* sp = s_feat2 + p * PLANE;

        int4 xp[4];
        #pragma unroll
        for (int g = 0; g < 4; ++g) xp[g] = s_xpack[(px << 2) + g];

        float ax = 0.0f, ay = 0.0f;
        #pragma unroll
        for (int gy = 0; gy < MAXG; ++gy) {
            if (gy < gh) {
                const int4 yp = s_ypack[(py << 2) + gy];
                const float wy0 = __int_as_float(yp.z);
                const float wy1 = __int_as_float(yp.w);
                #pragma unroll
                for (int gx = 0; gx < MAXG; ++gx) {
                    if (gx < gw) {
                        const float wx0 = __int_as_float(xp[gx].z);
                        const float wx1 = __int_as_float(xp[gx].w);
                        const float2 v00 = sp[yp.x + xp[gx].x];
                        const float2 v01 = sp[yp.x + xp[gx].y];
                        const float2 v10 = sp[yp.y + xp[gx].x];
                        const float2 v11 = sp[yp.y + xp[gx].y];
                        ax += wy0 * (wx0 * v00.x + wx1 * v01.x)
                            + wy1 * (wx0 * v10.x + wx1 * v11.x);
                        ay += wy0 * (wx0 * v00.y + wx1 * v01.y)
                            + wy1 * (wx0 * v10.y + wx1 * v11.y);
                    }
                }
            }
        }
        const size_t ob = ((size_t)n * C + cblk * CPB + 2 * p) * 49 + pix;
        __builtin_nontemporal_store(ax * inv_count, &out[ob]);        // channel 2p
        __builtin_nontemporal_store(ay * inv_count, &out[ob + 49]);   // channel 2p+1
    }
}

extern "C" void kernel_launch(void* const* d_in, const int* in_sizes, int n_in,
                              void* d_out, int out_size, void* d_ws, size_t ws_size,
                              hipStream_t stream) {
    const float* feat = (const float*)d_in[0];
    const float* rois = (const float*)d_in[1];
    float* out = (float*)d_out;

    const int C = 256, H = 200, W = 272;
    const int N = in_sizes[1] / 5;   // 512

    dim3 grid(N, C / CPB);           // 512 x 32: n fast (verified-best order)
    roi_align_kernel<<<grid, 256, 0, stream>>>(feat, rois, out, C, H, W);
}